// Round 4
// baseline (9198.826 us; speedup 1.0000x reference)
//
#include <hip/hip_runtime.h>
#include <hip/hip_bf16.h>
#include <hip/hip_cooperative_groups.h>

namespace cg = cooperative_groups;

// ELA forward on MI355X.
//  pack_x           : x fp32 -> bf16 seq in MFMA A-fragment tile order (staged in d_out)
//  pack_B           : {W,R} fp32 -> bf16 MFMA B-fragment tile order (into ws; W-pack and
//                     R-pack time-share the same region)
//  pre_gemm_packed  : pre = seq @ W{1,2}; all-bf16, global_load_lds both operands
//  persistent_step  : ONE cooperative kernel runs all 48 recurrence steps.
//                     256 blocks x 512 thr (1 block/CU). Per step: phase A = 6 MFMA
//                     col-fragments/block (K-split 8 waves, LDS reduce) -> Gbuf;
//                     grid.sync; phase B = gates on 384 feature-units (wave0/wave1),
//                     c/n/m state in registers; grid.sync; h ping-pong swap.
//  step_kernel x48  : fallback path if cooperative launch unavailable.
//  conv_gn_kernel   : grouped conv1d + GroupNorm + sigmoid
//  final_kernel     : out = xh[b,c,i] * xw[b,c,j] * x[b,c,i,j]
//
// HARD CONSTRAINT (learned round 1): NEVER write input buffers (d_in[*]).

typedef float  f32x4 __attribute__((ext_vector_type(4)));
typedef __bf16 v8bf  __attribute__((ext_vector_type(8)));
typedef __bf16 v4bf  __attribute__((ext_vector_type(4)));

#define MFMA16(a, b, c) __builtin_amdgcn_mfma_f32_16x16x32_bf16((a), (b), (c), 0, 0, 0)

// ---- ws layout (bytes). Base block = 40.1 MB. Packs appended (ws >= 191MB verified). ----
static constexpr size_t OFF_PREP = 0;            // bf16 pre, C-frag order: 2*48*768*64*4
static constexpr size_t SZ_PREP  = 37748736;
static constexpr size_t OFF_H0   = 37748736;     // h ping (A-frag, 2 stacks): 2*96*64*8*2
static constexpr size_t OFF_H1   = 37945344;     // h pong
static constexpr size_t OFF_C    = 38141952;     // c state fp32 (fallback path only)
static constexpr size_t OFF_N    = 38535168;
static constexpr size_t OFF_M    = 38928384;
static constexpr size_t OFF_YS   = 39321600;     // y sums fp32: 2*16*3072*4
static constexpr size_t OFF_GATE = 39714816;     // sigmoid gates fp32: 2*16*3072*4
static constexpr size_t BASE_END = 40108032;
static constexpr size_t SZ_RPACK = 75497472;     // one packed 3072x12288 bf16
static constexpr size_t OFF_RA   = BASE_END;     // W-pack lives here first, then R-pack
static constexpr size_t OFF_RB   = BASE_END + SZ_RPACK;
static constexpr size_t END_A    = OFF_RB + SZ_RPACK;   // 191,102,976

__device__ __forceinline__ void gl_lds16(const void* g, void* l) {
    __builtin_amdgcn_global_load_lds(
        (const __attribute__((address_space(1))) unsigned int*)g,
        (__attribute__((address_space(3))) unsigned int*)l, 16, 0, 0);
}

__global__ __launch_bounds__(256) void zero_kernel(f32x4* __restrict__ p, int n) {
    int i = blockIdx.x * 256 + threadIdx.x;
    if (i < n) { f32x4 z = 0.0f; p[i] = z; }
}

// x[16,64,48,48] -> seq A-pack: [mb 6][kc 96][sub 8][lane 64][8] bf16, row r = t*16+b
__global__ __launch_bounds__(256) void pack_x_kernel(const float* __restrict__ x,
                                                     __bf16* __restrict__ dst) {
    int gi = blockIdx.x * 256 + threadIdx.x;   // < 294912
    int lane = gi & 63;
    int rest = gi >> 6;
    int sub = rest & 7; rest >>= 3;
    int kc = rest % 96, mb = rest / 96;
    int r = mb * 128 + sub * 16 + (lane & 15);
    int t = r >> 4, b = r & 15;
    int k = kc * 32 + (lane >> 4) * 8;
    const f32x4* s = (const f32x4*)(x + (size_t)b * 147456 + (size_t)t * 3072 + k);
    f32x4 v0 = s[0], v1 = s[1];
    v8bf o;
#pragma unroll
    for (int j = 0; j < 4; ++j) { o[j] = (__bf16)v0[j]; o[4 + j] = (__bf16)v1[j]; }
    ((v8bf*)dst)[gi] = o;
}

// [3072,12288] fp32 -> B-pack [nb 96][kc 96][sub 8][lane 64][8] bf16 (via LDS transpose)
__global__ __launch_bounds__(256) void pack_B_kernel(const float* __restrict__ src0,
                                                     const float* __restrict__ src1,
                                                     __bf16* __restrict__ dst0,
                                                     __bf16* __restrict__ dst1) {
    int nb = blockIdx.x, kc = blockIdx.y, m = blockIdx.z;
    const float* src = m ? src1 : src0;
    __bf16* dst = m ? dst1 : dst0;
    int tid = threadIdx.x;
    __shared__ float tile[32][133];
    int kr = tid >> 3, nc0 = (tid & 7) * 16;
    const f32x4* s4 = (const f32x4*)(src + (size_t)(kc * 32 + kr) * 12288 + nb * 128 + nc0);
    f32x4 v0 = s4[0], v1 = s4[1], v2 = s4[2], v3 = s4[3];
#pragma unroll
    for (int r = 0; r < 4; ++r) {
        tile[kr][nc0 + r]      = v0[r];
        tile[kr][nc0 + 4 + r]  = v1[r];
        tile[kr][nc0 + 8 + r]  = v2[r];
        tile[kr][nc0 + 12 + r] = v3[r];
    }
    __syncthreads();
    __bf16* db = dst + (size_t)(nb * 96 + kc) * 4096;
#pragma unroll
    for (int c = 0; c < 2; ++c) {
        int lidx = tid * 2 + c;
        int sub = lidx >> 6, lane = lidx & 63;
        int kb = (lane >> 4) * 8, nn = sub * 16 + (lane & 15);
        v8bf o;
#pragma unroll
        for (int j = 0; j < 8; ++j) o[j] = (__bf16)tile[kb + j][nn];
        ((v8bf*)db)[lidx] = o;
    }
}

// pre = seq @ W, 128x128 tile, BK=32, BOTH operands pre-packed bf16 via global_load_lds.
__global__ __launch_bounds__(256) void pre_gemm_packed(const __bf16* __restrict__ Apack,
                                                       const __bf16* __restrict__ Bp0,
                                                       const __bf16* __restrict__ Bp1,
                                                       __bf16* __restrict__ preP) {
    int nb = blockIdx.x, mb = blockIdx.y, stack = blockIdx.z;
    const char* Bpack = (const char*)(stack ? Bp1 : Bp0);
    int tid = threadIdx.x, wave = tid >> 6, lane = tid & 63;
    __shared__ alignas(16) __bf16 As[4096];
    __shared__ alignas(16) __bf16 Bs[4096];
    f32x4 acc[4][4];
#pragma unroll
    for (int i = 0; i < 4; ++i)
#pragma unroll
        for (int j = 0; j < 4; ++j) acc[i][j] = 0.0f;

    for (int kc = 0; kc < 96; ++kc) {
        size_t atile = (size_t)(mb * 96 + kc) * 8192;
        size_t btile = (size_t)(nb * 96 + kc) * 8192;
        int chunk = wave * 2048;
        gl_lds16((const char*)Apack + atile + chunk + lane * 16,        (char*)As + chunk);
        gl_lds16((const char*)Apack + atile + chunk + 1024 + lane * 16, (char*)As + chunk + 1024);
        gl_lds16(Bpack + btile + chunk + lane * 16,        (char*)Bs + chunk);
        gl_lds16(Bpack + btile + chunk + 1024 + lane * 16, (char*)Bs + chunk + 1024);
        __syncthreads();
        const v8bf* A8 = (const v8bf*)As;
        const v8bf* B8 = (const v8bf*)Bs;
        v8bf a[4], b[4];
#pragma unroll
        for (int mi = 0; mi < 4; ++mi) a[mi] = A8[((wave >> 1) * 4 + mi) * 64 + lane];
#pragma unroll
        for (int ni = 0; ni < 4; ++ni) b[ni] = B8[((wave & 1) * 4 + ni) * 64 + lane];
#pragma unroll
        for (int mi = 0; mi < 4; ++mi)
#pragma unroll
            for (int ni = 0; ni < 4; ++ni) acc[mi][ni] = MFMA16(a[mi], b[ni], acc[mi][ni]);
        __syncthreads();
    }
#pragma unroll
    for (int mi = 0; mi < 4; ++mi)
#pragma unroll
        for (int ni = 0; ni < 4; ++ni) {
            int mt = mb * 8 + (wave >> 1) * 4 + mi;   // == t
            int nt4 = nb * 8 + (wave & 1) * 4 + ni;   // n-tile in [0,768)
            v4bf o;
#pragma unroll
            for (int r = 0; r < 4; ++r) o[r] = (__bf16)acc[mi][ni][r];
            ((v4bf*)preP)[(((size_t)stack * 48 + mt) * 768 + nt4) * 64 + lane] = o;
        }
}

// ---------------- persistent cooperative recurrence ----------------
// 256 blocks x 512 threads. Block b: phase-A fragments fid = b*6..b*6+5
// (fid = stack*768 + col-tile; 768 tiles per stack, so no block spans stacks).
// Phase B: unit u in [0,384): u<256 -> block u wave0; u>=256 -> block u-256 wave1.
__global__ __launch_bounds__(512) void persistent_step(
    const __bf16* __restrict__ Rp0, const __bf16* __restrict__ Rp1,
    __bf16* __restrict__ h0, __bf16* __restrict__ h1,
    const __bf16* __restrict__ preP,
    const float* __restrict__ bias1, const float* __restrict__ bias2,
    float* __restrict__ ysum, f32x4* __restrict__ Gbuf) {
    cg::grid_group grid = cg::this_grid();
    int b = blockIdx.x;
    int tid = threadIdx.x, wave = tid >> 6, lane = tid & 63;

    // --- phase A setup ---
    int stackA = b >> 7;
    const v8bf* Rp = (const v8bf*)(stackA ? Rp1 : Rp0);
    int ct0 = (b & 127) * 6;
    size_t baseB[6];
#pragma unroll
    for (int i = 0; i < 6; ++i) {
        int ct = ct0 + i;
        baseB[i] = (size_t)(ct >> 3) * 49152 + (size_t)(ct & 7) * 64 + lane;
    }
    int kcs = wave * 12;

    // --- phase B setup ---
    int u = -1;
    if (wave == 0) u = b;
    else if (wave == 1 && b < 128) u = 256 + b;
    int su = 0, ntu = 0, fcol = 0, bq = 0, yidx = 0;
    const float* biasB = bias1;
    if (u >= 0) {
        su = (u >= 192) ? 1 : 0;
        ntu = u - su * 192;
        fcol = ntu * 16 + (lane & 15);
        bq = (lane >> 4) * 4;
        biasB = su ? bias2 : bias1;
    }
    f32x4 cc = 0.0f, nn = 0.0f, mm = 0.0f;   // register-resident state across all 48 steps

    const __bf16* hr = h0;
    __bf16* hwp = h1;

    __shared__ f32x4 red[8][6][64];

    for (int t = 0; t < 48; ++t) {
        // ---------- phase A: 6 fragments, K-split over 8 waves ----------
        const v8bf* hA = (const v8bf*)hr + (size_t)stackA * 96 * 64;
        f32x4 acc[6];
#pragma unroll
        for (int i = 0; i < 6; ++i) acc[i] = 0.0f;
#pragma unroll 4
        for (int kk = 0; kk < 12; ++kk) {
            int kc = kcs + kk;
            v8bf a = hA[(size_t)kc * 64 + lane];
            v8bf bb[6];
#pragma unroll
            for (int i = 0; i < 6; ++i) bb[i] = Rp[baseB[i] + (size_t)kc * 512];
#pragma unroll
            for (int i = 0; i < 6; ++i) acc[i] = MFMA16(a, bb[i], acc[i]);
        }
#pragma unroll
        for (int i = 0; i < 6; ++i) red[wave][i][lane] = acc[i];
        __syncthreads();
        if (wave < 6) {
            f32x4 s = red[0][wave][lane];
#pragma unroll
            for (int w = 1; w < 8; ++w) s += red[w][wave][lane];
            Gbuf[(size_t)(b * 6 + wave) * 64 + lane] = s;
        }
        __threadfence();
        grid.sync();

        // ---------- phase B: gates on 384 feature-units ----------
        if (u >= 0) {
            f32x4 g[4];
#pragma unroll
            for (int gi = 0; gi < 4; ++gi) {
                int fid = su * 768 + gi * 192 + ntu;
                g[gi] = Gbuf[(size_t)fid * 64 + lane];
                v4bf pv = ((const v4bf*)preP)[(((size_t)su * 48 + t) * 768 + (gi * 192 + ntu)) * 64 + lane];
                float bv = biasB[gi * 3072 + fcol];
#pragma unroll
                for (int r = 0; r < 4; ++r) g[gi][r] += (float)pv[r] + bv;
            }
            int kc2 = fcol >> 5, ko = fcol & 31;
            __bf16* hwB = hwp + ((size_t)su * 96 + kc2) * 512 + (size_t)(ko >> 3) * 128 + (ko & 7);
            int flat = t * 3072 + fcol;
            int cch = flat / 2304;
            int rem = flat - cch * 2304;
            int uu = rem / 48;
            int vv = rem - uu * 48;
            yidx = cch * 48 + (su ? uu : vv);
            float* yb = ysum + (size_t)su * 16 * 3072;
#pragma unroll
            for (int r = 0; r < 4; ++r) {
                int brow = bq + r;
                float it = g[0][r], ft = g[1][r], zt = g[2][r], ot = g[3][r];
                float mnew = fmaxf(ft + mm[r], it);
                float iv = __expf(it - mnew);
                float fv = __expf(ft + mm[r] - mnew);
                float cnew = fv * cc[r] + iv * tanhf(zt);
                float nnew = fv * nn[r] + iv;
                float sg = 1.0f / (1.0f + __expf(-ot));
                float h = sg * cnew / (nnew + 1e-6f);
                cc[r] = cnew; nn[r] = nnew; mm[r] = mnew;
                hwB[(size_t)brow * 8] = (__bf16)h;
                atomicAdd(yb + (size_t)brow * 3072 + yidx, h);
            }
        }
        __threadfence();
        grid.sync();

        const __bf16* tmp = hr; hr = hwp; hwp = (__bf16*)tmp;
    }
}

// ---------------- fallback: one launch per step (round-2 verified) ----------------
__global__ __launch_bounds__(512) void step_kernel(
    const __bf16* __restrict__ Rp0, const __bf16* __restrict__ Rp1,
    const __bf16* __restrict__ hread, __bf16* __restrict__ hwrite,
    const __bf16* __restrict__ preP,
    const float* __restrict__ bias1, const float* __restrict__ bias2,
    float* __restrict__ cbuf, float* __restrict__ nbuf, float* __restrict__ mbuf,
    float* __restrict__ ysum, int t) {
    int nt = blockIdx.x, stack = blockIdx.y;
    int tid = threadIdx.x, wave = tid >> 6, lane = tid & 63;
    const v8bf* Rp = (const v8bf*)(stack ? Rp1 : Rp0);
    const v8bf* hA = (const v8bf*)hread + (size_t)stack * 96 * 64;
    int sub = nt & 7;
    size_t base[4];
#pragma unroll
    for (int i = 0; i < 4; ++i) {
        int nb = i * 24 + (nt >> 3);
        base[i] = (size_t)nb * 49152 + (size_t)sub * 64 + lane;
    }
    int kcs = wave * 12;
    f32x4 acc[4];
#pragma unroll
    for (int i = 0; i < 4; ++i) acc[i] = 0.0f;
#pragma unroll 4
    for (int kk = 0; kk < 12; ++kk) {
        int kc = kcs + kk;
        v8bf a = hA[(size_t)kc * 64 + lane];
        v8bf bb[4];
#pragma unroll
        for (int i = 0; i < 4; ++i) bb[i] = Rp[base[i] + (size_t)kc * 512];
#pragma unroll
        for (int i = 0; i < 4; ++i) acc[i] = MFMA16(a, bb[i], acc[i]);
    }

    __shared__ f32x4 red4[8][4][64];
#pragma unroll
    for (int i = 0; i < 4; ++i) red4[wave][i][lane] = acc[i];
    __syncthreads();

    if (wave == 0) {
        const float* bias = stack ? bias2 : bias1;
        f32x4 g[4];
#pragma unroll
        for (int i = 0; i < 4; ++i) {
            f32x4 s = red4[0][i][lane];
#pragma unroll
            for (int w = 1; w < 8; ++w) s += red4[w][i][lane];
            g[i] = s;
        }
        int fcol = nt * 16 + (lane & 15);
        int bq = (lane >> 4) * 4;
#pragma unroll
        for (int i = 0; i < 4; ++i) {
            v4bf pv = ((const v4bf*)preP)[(((size_t)stack * 48 + t) * 768 + (i * 192 + nt)) * 64 + lane];
            float bv = bias[i * 3072 + fcol];
#pragma unroll
            for (int r = 0; r < 4; ++r) g[i][r] += (float)pv[r] + bv;
        }
        size_t sidx = ((size_t)stack * 192 + nt) * 64 + lane;
        f32x4 cc = ((f32x4*)cbuf)[sidx];
        f32x4 nn = ((f32x4*)nbuf)[sidx];
        f32x4 mm = ((f32x4*)mbuf)[sidx];
        int kc = fcol >> 5, ko = fcol & 31;
        __bf16* hw = hwrite + ((size_t)stack * 96 + kc) * 512 + (size_t)(ko >> 3) * 128 + (ko & 7);
        int flat = t * 3072 + fcol;
        int cch = flat / 2304;
        int rem = flat - cch * 2304;
        int uu = rem / 48;
        int vv = rem - uu * 48;
        int yidx = cch * 48 + (stack ? uu : vv);
        float* yb = ysum + (size_t)stack * 16 * 3072;
#pragma unroll
        for (int r = 0; r < 4; ++r) {
            int brow = bq + r;
            float it = g[0][r], ft = g[1][r], zt = g[2][r], ot = g[3][r];
            float mnew = fmaxf(ft + mm[r], it);
            float iv = __expf(it - mnew);
            float fv = __expf(ft + mm[r] - mnew);
            float cnew = fv * cc[r] + iv * tanhf(zt);
            float nnew = fv * nn[r] + iv;
            float sg = 1.0f / (1.0f + __expf(-ot));
            float h = sg * cnew / (nnew + 1e-6f);
            cc[r] = cnew; nn[r] = nnew; mm[r] = mnew;
            hw[(size_t)brow * 8] = (__bf16)h;
            atomicAdd(yb + (size_t)brow * 3072 + yidx, h);
        }
        ((f32x4*)cbuf)[sidx] = cc;
        ((f32x4*)nbuf)[sidx] = nn;
        ((f32x4*)mbuf)[sidx] = mm;
    }
}

// grouped conv1d (K=5, 8 groups of 8ch) + GroupNorm(16 groups) + sigmoid, per (which, b)
__global__ __launch_bounds__(256) void conv_gn_kernel(const float* __restrict__ ysum,
                                                      const float* __restrict__ cw,
                                                      const float* __restrict__ gamma,
                                                      const float* __restrict__ beta,
                                                      float* __restrict__ gatebuf) {
    int bi = blockIdx.x;
    int s = bi >> 4, b = bi & 15;
    int tid = threadIdx.x;
    __shared__ float in0[3072], cvout[3072], cws[2560];
    __shared__ float r1[16][16], r2[16][16], mu_s[16], rs_s[16];
    const float* src = ysum + (size_t)(s * 16 + b) * 3072;
    for (int e = tid; e < 3072; e += 256) in0[e] = src[e] * (1.0f / 48.0f);
    for (int e = tid; e < 2560; e += 256) cws[e] = cw[e];
    __syncthreads();
    for (int e = tid; e < 3072; e += 256) {
        int co = e / 48, p = e - co * 48;
        int g = co >> 3;
        const float* wrow = cws + co * 40;
        const float* irow = in0 + g * 8 * 48;
        float a = 0.f;
#pragma unroll
        for (int ci = 0; ci < 8; ++ci)
#pragma unroll
            for (int q = 0; q < 5; ++q) {
                int pp = p + q - 2;
                if (pp >= 0 && pp < 48) a += wrow[ci * 5 + q] * irow[ci * 48 + pp];
            }
        cvout[e] = a;
    }
    __syncthreads();
    int gn = tid >> 4, ln = tid & 15;
    float s1 = 0.f, s2 = 0.f;
    for (int ii = ln; ii < 192; ii += 16) {
        float v = cvout[gn * 192 + ii];
        s1 += v; s2 += v * v;
    }
    r1[gn][ln] = s1; r2[gn][ln] = s2;
    __syncthreads();
    if (tid < 16) {
        float a = 0.f, c2 = 0.f;
        for (int ii = 0; ii < 16; ++ii) { a += r1[tid][ii]; c2 += r2[tid][ii]; }
        float mu = a * (1.0f / 192.0f);
        float var = c2 * (1.0f / 192.0f) - mu * mu;
        mu_s[tid] = mu;
        rs_s[tid] = rsqrtf(var + 1e-5f);
    }
    __syncthreads();
    float* dst = gatebuf + (size_t)(s * 16 + b) * 3072;
    for (int e = tid; e < 3072; e += 256) {
        int c = e / 48;
        int gg = c >> 2;
        float xn = (cvout[e] - mu_s[gg]) * rs_s[gg] * gamma[c] + beta[c];
        dst[e] = 1.0f / (1.0f + __expf(-xn));
    }
}

__global__ __launch_bounds__(256) void final_kernel(const float* __restrict__ x,
                                                    const float* __restrict__ gatebuf,
                                                    float* __restrict__ out) {
    int gid = blockIdx.x * 256 + threadIdx.x;  // < 589824 float4s
    int wi4 = gid % 12;
    int rest = gid / 12;
    int hi = rest % 48;
    int bc = rest / 48;
    int b = bc >> 6, c = bc & 63;
    f32x4 xv = ((const f32x4*)x)[gid];
    float gh = gatebuf[(size_t)(16 + b) * 3072 + c * 48 + hi];        // s=1 (y2) -> x_h[hi]
    f32x4 gw = *(const f32x4*)(gatebuf + (size_t)b * 3072 + c * 48 + wi4 * 4);  // s=0 -> x_w[wi]
    f32x4 o;
#pragma unroll
    for (int k = 0; k < 4; ++k) o[k] = xv[k] * gh * gw[k];
    ((f32x4*)out)[gid] = o;
}

extern "C" void kernel_launch(void* const* d_in, const int* in_sizes, int n_in,
                              void* d_out, int out_size, void* d_ws, size_t ws_size,
                              hipStream_t stream) {
    const float* x     = (const float*)d_in[0];
    const float* W1    = (const float*)d_in[1];
    const float* R1    = (const float*)d_in[2];
    const float* b1    = (const float*)d_in[3];
    const float* W2    = (const float*)d_in[4];
    const float* R2    = (const float*)d_in[5];
    const float* b2    = (const float*)d_in[6];
    const float* cw    = (const float*)d_in[7];
    const float* gamma = (const float*)d_in[8];
    const float* beta  = (const float*)d_in[9];

    char* ws = (char*)d_ws;
    __bf16* seqA = (__bf16*)d_out;               // scratch; dead after pre_gemm
    __bf16* preP = (__bf16*)(ws + OFF_PREP);
    __bf16* h0   = (__bf16*)(ws + OFF_H0);
    __bf16* h1   = (__bf16*)(ws + OFF_H1);
    float* cbuf  = (float*)(ws + OFF_C);
    float* nbuf  = (float*)(ws + OFF_N);
    float* mbuf  = (float*)(ws + OFF_M);
    float* ysum  = (float*)(ws + OFF_YS);
    float* gate  = (float*)(ws + OFF_GATE);
    f32x4* gbuf  = (f32x4*)d_out;                // 1.57 MB, reuses dead seqA region

    bool big_ws = ws_size >= END_A;   // rounds 0/2/3 passed via this path
    __bf16* PA = (__bf16*)(ws + OFF_RA);   // pack region (time-shared: W-pack then R-pack)
    __bf16* PB = (__bf16*)(ws + OFF_RB);

    pack_x_kernel<<<1152, 256, 0, stream>>>(x, seqA);
    if (big_ws) {
        pack_B_kernel<<<dim3(96, 96, 2), 256, 0, stream>>>(W1, W2, PA, PB);
        pre_gemm_packed<<<dim3(96, 6, 2), 256, 0, stream>>>(seqA, PA, PB, preP);
        pack_B_kernel<<<dim3(96, 96, 2), 256, 0, stream>>>(R1, R2, PA, PB);
    } else {
        pack_B_kernel<<<dim3(96, 96, 2), 256, 0, stream>>>(R1, R2, PA, PB);
        pre_gemm_packed<<<dim3(96, 6, 2), 256, 0, stream>>>(seqA, PA, PB, preP);
    }
    zero_kernel<<<480, 256, 0, stream>>>((f32x4*)(ws + OFF_H0), 122880);

    // Persistent cooperative recurrence (all 48 steps, 2 grid-syncs/step).
    {
        const __bf16* a0 = PA; const __bf16* a1 = PB;
        __bf16* ph0 = h0; __bf16* ph1 = h1;
        const __bf16* pp = preP;
        const float* pb1 = b1; const float* pb2 = b2;
        float* pys = ysum; f32x4* pg = gbuf;
        void* args[] = { (void*)&a0, (void*)&a1, (void*)&ph0, (void*)&ph1,
                         (void*)&pp, (void*)&pb1, (void*)&pb2, (void*)&pys, (void*)&pg };
        hipError_t err = hipLaunchCooperativeKernel(
            reinterpret_cast<void*>(persistent_step), dim3(256), dim3(512),
            args, 0, stream);
        if (err != hipSuccess) {
            // fallback: classic 48-launch loop
            for (int t = 0; t < 48; ++t) {
                const __bf16* hr = (t & 1) ? h1 : h0;
                __bf16* hw       = (t & 1) ? h0 : h1;
                step_kernel<<<dim3(192, 2), 512, 0, stream>>>(PA, PB, hr, hw, preP, b1, b2,
                                                              cbuf, nbuf, mbuf, ysum, t);
            }
        }
    }

    conv_gn_kernel<<<32, 256, 0, stream>>>(ysum, cw, gamma, beta, gate);
    final_kernel<<<2304, 256, 0, stream>>>(x, gate, (float*)d_out);
}

// Round 6
// 5194.670 us; speedup vs baseline: 1.7708x; 1.7708x over previous
//
#include <hip/hip_runtime.h>
#include <hip/hip_bf16.h>

// ELA forward on MI355X.
//  pack_x           : x fp32 -> bf16 seq in MFMA A-fragment tile order (staged in d_out)
//  pack_B           : {W,R} fp32 -> bf16 MFMA B-fragment tile order (into ws; W-pack and
//                     R-pack time-share the same region)
//  pre_gemm_packed  : pre = seq @ W{1,2}; all-bf16, global_load_lds both operands
//  persistent_step  : ONE cooperative kernel, 192 blocks x 512 thr (1 block/CU, strictly
//                     under the 256-block coop size proven in round 4), runs all 48 steps.
//                     Block b owns TWO gate-units: (stack0, nt=b) on waves 0-3 and
//                     (stack1, nt=b) on waves 4-7 — the round-0-verified 4-wave/24-kc
//                     geometry per unit. One custom agent-scope acq/rel barrier per step
//                     with a BOUNDED spin (cannot hang). c/n/m state in wave-0/4 registers.
//  step_kernel x48  : fallback path if cooperative launch unavailable.
//  conv_gn_kernel   : grouped conv1d + GroupNorm + sigmoid
//  final_kernel     : out = xh[b,c,i] * xw[b,c,j] * x[b,c,i,j]
//
// HARD CONSTRAINTS (learned):
//  - round 1: NEVER write input buffers (d_in[*]) — harness replays without restoring.
//  - round 4: cg::grid.sync costs ~93us/sync at 256 blocks — never use it.
//  - round 5: 384-block coop launch + relaxed-spin barrier hung the queue; stay <=256
//    blocks and bound every spin loop.

typedef float  f32x4 __attribute__((ext_vector_type(4)));
typedef __bf16 v8bf  __attribute__((ext_vector_type(8)));
typedef __bf16 v4bf  __attribute__((ext_vector_type(4)));

#define MFMA16(a, b, c) __builtin_amdgcn_mfma_f32_16x16x32_bf16((a), (b), (c), 0, 0, 0)

// ---- ws layout (bytes). Base block = 40.1 MB. Packs appended (ws >= 191MB verified). ----
static constexpr size_t OFF_PREP = 0;            // bf16 pre, C-frag order: 2*48*768*64*4
static constexpr size_t SZ_PREP  = 37748736;
static constexpr size_t OFF_H0   = 37748736;     // h ping (A-frag, 2 stacks): 2*96*64*8*2
static constexpr size_t OFF_H1   = 37945344;     // h pong
static constexpr size_t OFF_C    = 38141952;     // c state fp32 (fallback path only)
static constexpr size_t OFF_N    = 38535168;
static constexpr size_t OFF_M    = 38928384;
static constexpr size_t OFF_YS   = 39321600;     // y sums fp32: 2*16*3072*4
static constexpr size_t OFF_GATE = 39714816;     // sigmoid gates fp32 (also: barrier word)
static constexpr size_t BASE_END = 40108032;
static constexpr size_t SZ_RPACK = 75497472;     // one packed 3072x12288 bf16
static constexpr size_t OFF_RA   = BASE_END;     // W-pack lives here first, then R-pack
static constexpr size_t OFF_RB   = BASE_END + SZ_RPACK;
static constexpr size_t END_A    = OFF_RB + SZ_RPACK;   // 191,102,976

__device__ __forceinline__ void gl_lds16(const void* g, void* l) {
    __builtin_amdgcn_global_load_lds(
        (const __attribute__((address_space(1))) unsigned int*)g,
        (__attribute__((address_space(3))) unsigned int*)l, 16, 0, 0);
}

__global__ __launch_bounds__(256) void zero_kernel(f32x4* __restrict__ p, int n) {
    int i = blockIdx.x * 256 + threadIdx.x;
    if (i < n) { f32x4 z = 0.0f; p[i] = z; }
}

// x[16,64,48,48] -> seq A-pack: [mb 6][kc 96][sub 8][lane 64][8] bf16, row r = t*16+b
__global__ __launch_bounds__(256) void pack_x_kernel(const float* __restrict__ x,
                                                     __bf16* __restrict__ dst) {
    int gi = blockIdx.x * 256 + threadIdx.x;   // < 294912
    int lane = gi & 63;
    int rest = gi >> 6;
    int sub = rest & 7; rest >>= 3;
    int kc = rest % 96, mb = rest / 96;
    int r = mb * 128 + sub * 16 + (lane & 15);
    int t = r >> 4, b = r & 15;
    int k = kc * 32 + (lane >> 4) * 8;
    const f32x4* s = (const f32x4*)(x + (size_t)b * 147456 + (size_t)t * 3072 + k);
    f32x4 v0 = s[0], v1 = s[1];
    v8bf o;
#pragma unroll
    for (int j = 0; j < 4; ++j) { o[j] = (__bf16)v0[j]; o[4 + j] = (__bf16)v1[j]; }
    ((v8bf*)dst)[gi] = o;
}

// [3072,12288] fp32 -> B-pack [nb 96][kc 96][sub 8][lane 64][8] bf16 (via LDS transpose)
__global__ __launch_bounds__(256) void pack_B_kernel(const float* __restrict__ src0,
                                                     const float* __restrict__ src1,
                                                     __bf16* __restrict__ dst0,
                                                     __bf16* __restrict__ dst1) {
    int nb = blockIdx.x, kc = blockIdx.y, m = blockIdx.z;
    const float* src = m ? src1 : src0;
    __bf16* dst = m ? dst1 : dst0;
    int tid = threadIdx.x;
    __shared__ float tile[32][133];
    int kr = tid >> 3, nc0 = (tid & 7) * 16;
    const f32x4* s4 = (const f32x4*)(src + (size_t)(kc * 32 + kr) * 12288 + nb * 128 + nc0);
    f32x4 v0 = s4[0], v1 = s4[1], v2 = s4[2], v3 = s4[3];
#pragma unroll
    for (int r = 0; r < 4; ++r) {
        tile[kr][nc0 + r]      = v0[r];
        tile[kr][nc0 + 4 + r]  = v1[r];
        tile[kr][nc0 + 8 + r]  = v2[r];
        tile[kr][nc0 + 12 + r] = v3[r];
    }
    __syncthreads();
    __bf16* db = dst + (size_t)(nb * 96 + kc) * 4096;
#pragma unroll
    for (int c = 0; c < 2; ++c) {
        int lidx = tid * 2 + c;
        int sub = lidx >> 6, lane = lidx & 63;
        int kb = (lane >> 4) * 8, nn = sub * 16 + (lane & 15);
        v8bf o;
#pragma unroll
        for (int j = 0; j < 8; ++j) o[j] = (__bf16)tile[kb + j][nn];
        ((v8bf*)db)[lidx] = o;
    }
}

// pre = seq @ W, 128x128 tile, BK=32, BOTH operands pre-packed bf16 via global_load_lds.
__global__ __launch_bounds__(256) void pre_gemm_packed(const __bf16* __restrict__ Apack,
                                                       const __bf16* __restrict__ Bp0,
                                                       const __bf16* __restrict__ Bp1,
                                                       __bf16* __restrict__ preP) {
    int nb = blockIdx.x, mb = blockIdx.y, stack = blockIdx.z;
    const char* Bpack = (const char*)(stack ? Bp1 : Bp0);
    int tid = threadIdx.x, wave = tid >> 6, lane = tid & 63;
    __shared__ alignas(16) __bf16 As[4096];
    __shared__ alignas(16) __bf16 Bs[4096];
    f32x4 acc[4][4];
#pragma unroll
    for (int i = 0; i < 4; ++i)
#pragma unroll
        for (int j = 0; j < 4; ++j) acc[i][j] = 0.0f;

    for (int kc = 0; kc < 96; ++kc) {
        size_t atile = (size_t)(mb * 96 + kc) * 8192;
        size_t btile = (size_t)(nb * 96 + kc) * 8192;
        int chunk = wave * 2048;
        gl_lds16((const char*)Apack + atile + chunk + lane * 16,        (char*)As + chunk);
        gl_lds16((const char*)Apack + atile + chunk + 1024 + lane * 16, (char*)As + chunk + 1024);
        gl_lds16(Bpack + btile + chunk + lane * 16,        (char*)Bs + chunk);
        gl_lds16(Bpack + btile + chunk + 1024 + lane * 16, (char*)Bs + chunk + 1024);
        __syncthreads();
        const v8bf* A8 = (const v8bf*)As;
        const v8bf* B8 = (const v8bf*)Bs;
        v8bf a[4], b[4];
#pragma unroll
        for (int mi = 0; mi < 4; ++mi) a[mi] = A8[((wave >> 1) * 4 + mi) * 64 + lane];
#pragma unroll
        for (int ni = 0; ni < 4; ++ni) b[ni] = B8[((wave & 1) * 4 + ni) * 64 + lane];
#pragma unroll
        for (int mi = 0; mi < 4; ++mi)
#pragma unroll
            for (int ni = 0; ni < 4; ++ni) acc[mi][ni] = MFMA16(a[mi], b[ni], acc[mi][ni]);
        __syncthreads();
    }
#pragma unroll
    for (int mi = 0; mi < 4; ++mi)
#pragma unroll
        for (int ni = 0; ni < 4; ++ni) {
            int mt = mb * 8 + (wave >> 1) * 4 + mi;   // == t
            int nt4 = nb * 8 + (wave & 1) * 4 + ni;   // n-tile in [0,768)
            v4bf o;
#pragma unroll
            for (int r = 0; r < 4; ++r) o[r] = (__bf16)acc[mi][ni][r];
            ((v4bf*)preP)[(((size_t)stack * 48 + mt) * 768 + nt4) * 64 + lane] = o;
        }
}

// ---------------- persistent recurrence, 192 blocks, bounded custom barrier ----------------
__global__ __launch_bounds__(512) void persistent_step(
    const __bf16* __restrict__ Rp0, const __bf16* __restrict__ Rp1,
    __bf16* __restrict__ h0, __bf16* __restrict__ h1,
    const __bf16* __restrict__ preP,
    const float* __restrict__ bias1, const float* __restrict__ bias2,
    float* __restrict__ ysum, unsigned* __restrict__ bar) {
    int nt = blockIdx.x;                       // [0,192)
    int tid = threadIdx.x, wave = tid >> 6, lane = tid & 63;
    int s  = wave >> 2;                        // unit stack: waves 0-3 -> 0, waves 4-7 -> 1
    int wv = wave & 3;                         // K-split index within unit
    const v8bf* Rp = (const v8bf*)(s ? Rp1 : Rp0);
    int sub = nt & 7;
    size_t base[4];
#pragma unroll
    for (int i = 0; i < 4; ++i) {
        int nb = i * 24 + (nt >> 3);
        base[i] = (size_t)nb * 49152 + (size_t)sub * 64 + lane;  // + kc*512
    }
    int kcs = wv * 24;
    const float* bias = s ? bias2 : bias1;
    int fcol = nt * 16 + (lane & 15);
    int bq = (lane >> 4) * 4;
    int kc2 = fcol >> 5, ko = fcol & 31;
    float* yb = ysum + (size_t)s * 16 * 3072;

    f32x4 cc = 0.0f, nn = 0.0f, mm = 0.0f;     // register-resident sLSTM state (waves 0,4)
    const __bf16* hr = h0;
    __bf16* hwp = h1;

    __shared__ f32x4 red[2][4][4][64];         // [unit][wv][frag][lane]

    for (int t = 0; t < 48; ++t) {
        // ---- phase A: G-partial = h @ R, 4-wave K-split per unit (round-0 geometry) ----
        const v8bf* hA = (const v8bf*)hr + (size_t)s * 96 * 64;
        f32x4 acc[4];
#pragma unroll
        for (int i = 0; i < 4; ++i) acc[i] = 0.0f;
#pragma unroll 4
        for (int kk = 0; kk < 24; ++kk) {
            int kc = kcs + kk;
            v8bf a = hA[(size_t)kc * 64 + lane];
            v8bf bb[4];
#pragma unroll
            for (int i = 0; i < 4; ++i) bb[i] = Rp[base[i] + (size_t)kc * 512];
#pragma unroll
            for (int i = 0; i < 4; ++i) acc[i] = MFMA16(a, bb[i], acc[i]);
        }
#pragma unroll
        for (int i = 0; i < 4; ++i) red[s][wv][i][lane] = acc[i];
        __syncthreads();

        // ---- phase B: gates on wave 0 (unit stack0) and wave 4 (unit stack1) ----
        if (wv == 0) {
            f32x4 g[4];
#pragma unroll
            for (int i = 0; i < 4; ++i) {
                f32x4 sum = red[s][0][i][lane];
#pragma unroll
                for (int w = 1; w < 4; ++w) sum += red[s][w][i][lane];
                g[i] = sum;
            }
#pragma unroll
            for (int i = 0; i < 4; ++i) {
                v4bf pv = ((const v4bf*)preP)[(((size_t)s * 48 + t) * 768 + (i * 192 + nt)) * 64 + lane];
                float bv = bias[i * 3072 + fcol];
#pragma unroll
                for (int r = 0; r < 4; ++r) g[i][r] += (float)pv[r] + bv;
            }
            __bf16* hwB = hwp + ((size_t)s * 96 + kc2) * 512 + (size_t)(ko >> 3) * 128 + (ko & 7);
            int flat = t * 3072 + fcol;
            int cch = flat / 2304;
            int rem = flat - cch * 2304;
            int uu = rem / 48;
            int vv = rem - uu * 48;
            int yidx = cch * 48 + (s ? uu : vv);
#pragma unroll
            for (int r = 0; r < 4; ++r) {
                int brow = bq + r;
                float it = g[0][r], ft = g[1][r], zt = g[2][r], ot = g[3][r];
                float mnew = fmaxf(ft + mm[r], it);
                float iv = __expf(it - mnew);
                float fv = __expf(ft + mm[r] - mnew);
                float cnew = fv * cc[r] + iv * tanhf(zt);
                float nnew = fv * nn[r] + iv;
                float sg = 1.0f / (1.0f + __expf(-ot));
                float h = sg * cnew / (nnew + 1e-6f);
                cc[r] = cnew; nn[r] = nnew; mm[r] = mnew;
                hwB[(size_t)brow * 8] = (__bf16)h;
                atomicAdd(yb + (size_t)brow * 3072 + yidx, h);
            }
        }

        // ---- custom grid barrier: agent-scope acq/rel, BOUNDED spin (cannot hang) ----
        __threadfence();                       // push h writes to device-coherent point
        __syncthreads();
        if (tid == 0) {
            __hip_atomic_fetch_add(bar, 1u, __ATOMIC_ACQ_REL, __HIP_MEMORY_SCOPE_AGENT);
            unsigned tgt = (unsigned)(t + 1) * 192u;
            int guard = 0;
            while (__hip_atomic_load(bar, __ATOMIC_ACQUIRE, __HIP_MEMORY_SCOPE_AGENT) < tgt) {
                __builtin_amdgcn_s_sleep(2);
                if (++guard > 20000) break;    // safety valve: fail fast, never hang
            }
        }
        __syncthreads();
        __threadfence();                       // invalidate stale caches before reading new h

        const __bf16* tmp = hr; hr = hwp; hwp = (__bf16*)tmp;
    }
}

// ---------------- fallback: one launch per step (rounds 0/2/3 verified) ----------------
__global__ __launch_bounds__(512) void step_kernel(
    const __bf16* __restrict__ Rp0, const __bf16* __restrict__ Rp1,
    const __bf16* __restrict__ hread, __bf16* __restrict__ hwrite,
    const __bf16* __restrict__ preP,
    const float* __restrict__ bias1, const float* __restrict__ bias2,
    float* __restrict__ cbuf, float* __restrict__ nbuf, float* __restrict__ mbuf,
    float* __restrict__ ysum, int t) {
    int nt = blockIdx.x, stack = blockIdx.y;
    int tid = threadIdx.x, wave = tid >> 6, lane = tid & 63;
    const v8bf* Rp = (const v8bf*)(stack ? Rp1 : Rp0);
    const v8bf* hA = (const v8bf*)hread + (size_t)stack * 96 * 64;
    int sub = nt & 7;
    size_t base[4];
#pragma unroll
    for (int i = 0; i < 4; ++i) {
        int nb = i * 24 + (nt >> 3);
        base[i] = (size_t)nb * 49152 + (size_t)sub * 64 + lane;
    }
    int kcs = wave * 12;
    f32x4 acc[4];
#pragma unroll
    for (int i = 0; i < 4; ++i) acc[i] = 0.0f;
#pragma unroll 4
    for (int kk = 0; kk < 12; ++kk) {
        int kc = kcs + kk;
        v8bf a = hA[(size_t)kc * 64 + lane];
        v8bf bb[4];
#pragma unroll
        for (int i = 0; i < 4; ++i) bb[i] = Rp[base[i] + (size_t)kc * 512];
#pragma unroll
        for (int i = 0; i < 4; ++i) acc[i] = MFMA16(a, bb[i], acc[i]);
    }

    __shared__ f32x4 red4[8][4][64];
#pragma unroll
    for (int i = 0; i < 4; ++i) red4[wave][i][lane] = acc[i];
    __syncthreads();

    if (wave == 0) {
        const float* bias = stack ? bias2 : bias1;
        f32x4 g[4];
#pragma unroll
        for (int i = 0; i < 4; ++i) {
            f32x4 s = red4[0][i][lane];
#pragma unroll
            for (int w = 1; w < 8; ++w) s += red4[w][i][lane];
            g[i] = s;
        }
        int fcol = nt * 16 + (lane & 15);
        int bq = (lane >> 4) * 4;
#pragma unroll
        for (int i = 0; i < 4; ++i) {
            v4bf pv = ((const v4bf*)preP)[(((size_t)stack * 48 + t) * 768 + (i * 192 + nt)) * 64 + lane];
            float bv = bias[i * 3072 + fcol];
#pragma unroll
            for (int r = 0; r < 4; ++r) g[i][r] += (float)pv[r] + bv;
        }
        size_t sidx = ((size_t)stack * 192 + nt) * 64 + lane;
        f32x4 cc = ((f32x4*)cbuf)[sidx];
        f32x4 nn = ((f32x4*)nbuf)[sidx];
        f32x4 mm = ((f32x4*)mbuf)[sidx];
        int kc = fcol >> 5, ko = fcol & 31;
        __bf16* hw = hwrite + ((size_t)stack * 96 + kc) * 512 + (size_t)(ko >> 3) * 128 + (ko & 7);
        int flat = t * 3072 + fcol;
        int cch = flat / 2304;
        int rem = flat - cch * 2304;
        int uu = rem / 48;
        int vv = rem - uu * 48;
        int yidx = cch * 48 + (stack ? uu : vv);
        float* yb = ysum + (size_t)stack * 16 * 3072;
#pragma unroll
        for (int r = 0; r < 4; ++r) {
            int brow = bq + r;
            float it = g[0][r], ft = g[1][r], zt = g[2][r], ot = g[3][r];
            float mnew = fmaxf(ft + mm[r], it);
            float iv = __expf(it - mnew);
            float fv = __expf(ft + mm[r] - mnew);
            float cnew = fv * cc[r] + iv * tanhf(zt);
            float nnew = fv * nn[r] + iv;
            float sg = 1.0f / (1.0f + __expf(-ot));
            float h = sg * cnew / (nnew + 1e-6f);
            cc[r] = cnew; nn[r] = nnew; mm[r] = mnew;
            hw[(size_t)brow * 8] = (__bf16)h;
            atomicAdd(yb + (size_t)brow * 3072 + yidx, h);
        }
        ((f32x4*)cbuf)[sidx] = cc;
        ((f32x4*)nbuf)[sidx] = nn;
        ((f32x4*)mbuf)[sidx] = mm;
    }
}

// grouped conv1d (K=5, 8 groups of 8ch) + GroupNorm(16 groups) + sigmoid, per (which, b)
__global__ __launch_bounds__(256) void conv_gn_kernel(const float* __restrict__ ysum,
                                                      const float* __restrict__ cw,
                                                      const float* __restrict__ gamma,
                                                      const float* __restrict__ beta,
                                                      float* __restrict__ gatebuf) {
    int bi = blockIdx.x;
    int s = bi >> 4, b = bi & 15;
    int tid = threadIdx.x;
    __shared__ float in0[3072], cvout[3072], cws[2560];
    __shared__ float r1[16][16], r2[16][16], mu_s[16], rs_s[16];
    const float* src = ysum + (size_t)(s * 16 + b) * 3072;
    for (int e = tid; e < 3072; e += 256) in0[e] = src[e] * (1.0f / 48.0f);
    for (int e = tid; e < 2560; e += 256) cws[e] = cw[e];
    __syncthreads();
    for (int e = tid; e < 3072; e += 256) {
        int co = e / 48, p = e - co * 48;
        int g = co >> 3;
        const float* wrow = cws + co * 40;
        const float* irow = in0 + g * 8 * 48;
        float a = 0.f;
#pragma unroll
        for (int ci = 0; ci < 8; ++ci)
#pragma unroll
            for (int q = 0; q < 5; ++q) {
                int pp = p + q - 2;
                if (pp >= 0 && pp < 48) a += wrow[ci * 5 + q] * irow[ci * 48 + pp];
            }
        cvout[e] = a;
    }
    __syncthreads();
    int gn = tid >> 4, ln = tid & 15;
    float s1 = 0.f, s2 = 0.f;
    for (int ii = ln; ii < 192; ii += 16) {
        float v = cvout[gn * 192 + ii];
        s1 += v; s2 += v * v;
    }
    r1[gn][ln] = s1; r2[gn][ln] = s2;
    __syncthreads();
    if (tid < 16) {
        float a = 0.f, c2 = 0.f;
        for (int ii = 0; ii < 16; ++ii) { a += r1[tid][ii]; c2 += r2[tid][ii]; }
        float mu = a * (1.0f / 192.0f);
        float var = c2 * (1.0f / 192.0f) - mu * mu;
        mu_s[tid] = mu;
        rs_s[tid] = rsqrtf(var + 1e-5f);
    }
    __syncthreads();
    float* dst = gatebuf + (size_t)(s * 16 + b) * 3072;
    for (int e = tid; e < 3072; e += 256) {
        int c = e / 48;
        int gg = c >> 2;
        float xn = (cvout[e] - mu_s[gg]) * rs_s[gg] * gamma[c] + beta[c];
        dst[e] = 1.0f / (1.0f + __expf(-xn));
    }
}

__global__ __launch_bounds__(256) void final_kernel(const float* __restrict__ x,
                                                    const float* __restrict__ gatebuf,
                                                    float* __restrict__ out) {
    int gid = blockIdx.x * 256 + threadIdx.x;  // < 589824 float4s
    int wi4 = gid % 12;
    int rest = gid / 12;
    int hi = rest % 48;
    int bc = rest / 48;
    int b = bc >> 6, c = bc & 63;
    f32x4 xv = ((const f32x4*)x)[gid];
    float gh = gatebuf[(size_t)(16 + b) * 3072 + c * 48 + hi];        // s=1 (y2) -> x_h[hi]
    f32x4 gw = *(const f32x4*)(gatebuf + (size_t)b * 3072 + c * 48 + wi4 * 4);  // s=0 -> x_w[wi]
    f32x4 o;
#pragma unroll
    for (int k = 0; k < 4; ++k) o[k] = xv[k] * gh * gw[k];
    ((f32x4*)out)[gid] = o;
}

extern "C" void kernel_launch(void* const* d_in, const int* in_sizes, int n_in,
                              void* d_out, int out_size, void* d_ws, size_t ws_size,
                              hipStream_t stream) {
    const float* x     = (const float*)d_in[0];
    const float* W1    = (const float*)d_in[1];
    const float* R1    = (const float*)d_in[2];
    const float* b1    = (const float*)d_in[3];
    const float* W2    = (const float*)d_in[4];
    const float* R2    = (const float*)d_in[5];
    const float* b2    = (const float*)d_in[6];
    const float* cw    = (const float*)d_in[7];
    const float* gamma = (const float*)d_in[8];
    const float* beta  = (const float*)d_in[9];

    char* ws = (char*)d_ws;
    __bf16* seqA = (__bf16*)d_out;               // scratch; dead after pre_gemm
    __bf16* preP = (__bf16*)(ws + OFF_PREP);
    __bf16* h0   = (__bf16*)(ws + OFF_H0);
    __bf16* h1   = (__bf16*)(ws + OFF_H1);
    float* cbuf  = (float*)(ws + OFF_C);
    float* nbuf  = (float*)(ws + OFF_N);
    float* mbuf  = (float*)(ws + OFF_M);
    float* ysum  = (float*)(ws + OFF_YS);
    float* gate  = (float*)(ws + OFF_GATE);
    unsigned* bar = (unsigned*)(ws + OFF_GATE);  // barrier word; gate region is fully
                                                 // overwritten only AFTER the steps

    bool big_ws = ws_size >= END_A;   // rounds 0/2/3/4 passed via this path
    __bf16* PA = (__bf16*)(ws + OFF_RA);   // pack region (time-shared: W-pack then R-pack)
    __bf16* PB = (__bf16*)(ws + OFF_RB);

    pack_x_kernel<<<1152, 256, 0, stream>>>(x, seqA);
    if (big_ws) {
        pack_B_kernel<<<dim3(96, 96, 2), 256, 0, stream>>>(W1, W2, PA, PB);
        pre_gemm_packed<<<dim3(96, 6, 2), 256, 0, stream>>>(seqA, PA, PB, preP);
        pack_B_kernel<<<dim3(96, 96, 2), 256, 0, stream>>>(R1, R2, PA, PB);
    } else {
        pack_B_kernel<<<dim3(96, 96, 2), 256, 0, stream>>>(R1, R2, PA, PB);
        pre_gemm_packed<<<dim3(96, 6, 2), 256, 0, stream>>>(seqA, PA, PB, preP);
    }
    // zero h0/h1/c/n/m/ysum AND the barrier word (1 extra f32x4 past OFF_GATE start)
    zero_kernel<<<481, 256, 0, stream>>>((f32x4*)(ws + OFF_H0), 122881);

    // Persistent recurrence: cooperative launch (co-residency guarantee) with the custom
    // bounded agent-scope barrier. 192 blocks — strictly under the proven 256-block size.
    {
        const __bf16* a0 = PA; const __bf16* a1 = PB;
        __bf16* ph0 = h0; __bf16* ph1 = h1;
        const __bf16* pp = preP;
        const float* pb1 = b1; const float* pb2 = b2;
        float* pys = ysum; unsigned* pbar = bar;
        void* args[] = { (void*)&a0, (void*)&a1, (void*)&ph0, (void*)&ph1,
                         (void*)&pp, (void*)&pb1, (void*)&pb2, (void*)&pys, (void*)&pbar };
        hipError_t err = hipLaunchCooperativeKernel(
            reinterpret_cast<void*>(persistent_step), dim3(192), dim3(512),
            args, 0, stream);
        if (err != hipSuccess) {
            // fallback: classic 48-launch loop (verified rounds 0/2/3)
            for (int t = 0; t < 48; ++t) {
                const __bf16* hr = (t & 1) ? h1 : h0;
                __bf16* hw       = (t & 1) ? h0 : h1;
                step_kernel<<<dim3(192, 2), 512, 0, stream>>>(PA, PB, hr, hw, preP, b1, b2,
                                                              cbuf, nbuf, mbuf, ysum, t);
            }
        }
    }

    conv_gn_kernel<<<32, 256, 0, stream>>>(ysum, cw, gamma, beta, gate);
    final_kernel<<<2304, 256, 0, stream>>>(x, gate, (float*)d_out);
}

// Round 7
// 2665.763 us; speedup vs baseline: 3.4507x; 1.9487x over previous
//
#include <hip/hip_runtime.h>
#include <hip/hip_bf16.h>

// ELA forward on MI355X.
//  pack_x           : x fp32 -> bf16 seq in MFMA A-fragment tile order (staged in d_out)
//  pack_B           : {W} fp32 -> bf16 MFMA B-fragment [nb][kc] tile order (for pre_gemm)
//  pack_R           : {R} fp32 -> bf16 B-fragments in UNIT-CONTIGUOUS order
//                     [nt 192][kc 96][i 4][lane 64][8] so each step wave streams one
//                     contiguous 48KB run instead of 4 streams strided at 8KB.
//  pre_gemm_packed  : pre = seq @ W{1,2}; all-bf16, global_load_lds both operands
//  step_kernel x48  : G = pre_t + h @ R (both stacks), 8-way K-split, depth-1 prefetch,
//                     fused sLSTM gates. (Persistent/coop variants abandoned: rounds 4-6
//                     measured grid.sync ~93us, custom barrier path = 101us/step vs 48.)
//  conv_gn_kernel   : grouped conv1d + GroupNorm + sigmoid
//  final_kernel     : out = xh[b,c,i] * xw[b,c,j] * x[b,c,i,j]
//
// HARD CONSTRAINTS (learned):
//  - round 1: NEVER write input buffers (d_in[*]) — harness replays without restoring.
//  - rounds 4-6: no cg::grid.sync, no >256-block coop, persistent step loses to multi-launch.

typedef float  f32x4 __attribute__((ext_vector_type(4)));
typedef __bf16 v8bf  __attribute__((ext_vector_type(8)));
typedef __bf16 v4bf  __attribute__((ext_vector_type(4)));

#define MFMA16(a, b, c) __builtin_amdgcn_mfma_f32_16x16x32_bf16((a), (b), (c), 0, 0, 0)

// ---- ws layout (bytes). Base block = 40.1 MB. Packs appended (ws >= 191MB verified). ----
static constexpr size_t OFF_PREP = 0;            // bf16 pre, C-frag order: 2*48*768*64*4
static constexpr size_t SZ_PREP  = 37748736;
static constexpr size_t OFF_H0   = 37748736;     // h ping (A-frag, 2 stacks): 2*96*64*8*2
static constexpr size_t OFF_H1   = 37945344;     // h pong
static constexpr size_t OFF_C    = 38141952;     // c state fp32: 2*192*64*4*4
static constexpr size_t OFF_N    = 38535168;
static constexpr size_t OFF_M    = 38928384;
static constexpr size_t OFF_YS   = 39321600;     // y sums fp32: 2*16*3072*4
static constexpr size_t OFF_GATE = 39714816;     // sigmoid gates fp32: 2*16*3072*4
static constexpr size_t BASE_END = 40108032;
static constexpr size_t SZ_RPACK = 75497472;     // one packed 3072x12288 bf16
static constexpr size_t OFF_RA   = BASE_END;     // W-pack lives here first, then R-pack
static constexpr size_t OFF_RB   = BASE_END + SZ_RPACK;
static constexpr size_t END_A    = OFF_RB + SZ_RPACK;   // 191,102,976

__device__ __forceinline__ void gl_lds16(const void* g, void* l) {
    __builtin_amdgcn_global_load_lds(
        (const __attribute__((address_space(1))) unsigned int*)g,
        (__attribute__((address_space(3))) unsigned int*)l, 16, 0, 0);
}

__global__ __launch_bounds__(256) void zero_kernel(f32x4* __restrict__ p, int n) {
    int i = blockIdx.x * 256 + threadIdx.x;
    if (i < n) { f32x4 z = 0.0f; p[i] = z; }
}

// x[16,64,48,48] -> seq A-pack: [mb 6][kc 96][sub 8][lane 64][8] bf16, row r = t*16+b
__global__ __launch_bounds__(256) void pack_x_kernel(const float* __restrict__ x,
                                                     __bf16* __restrict__ dst) {
    int gi = blockIdx.x * 256 + threadIdx.x;   // < 294912
    int lane = gi & 63;
    int rest = gi >> 6;
    int sub = rest & 7; rest >>= 3;
    int kc = rest % 96, mb = rest / 96;
    int r = mb * 128 + sub * 16 + (lane & 15);
    int t = r >> 4, b = r & 15;
    int k = kc * 32 + (lane >> 4) * 8;
    const f32x4* s = (const f32x4*)(x + (size_t)b * 147456 + (size_t)t * 3072 + k);
    f32x4 v0 = s[0], v1 = s[1];
    v8bf o;
#pragma unroll
    for (int j = 0; j < 4; ++j) { o[j] = (__bf16)v0[j]; o[4 + j] = (__bf16)v1[j]; }
    ((v8bf*)dst)[gi] = o;
}

// [3072,12288] fp32 -> B-pack [nb 96][kc 96][sub 8][lane 64][8] bf16 (via LDS transpose)
__global__ __launch_bounds__(256) void pack_B_kernel(const float* __restrict__ src0,
                                                     const float* __restrict__ src1,
                                                     __bf16* __restrict__ dst0,
                                                     __bf16* __restrict__ dst1) {
    int nb = blockIdx.x, kc = blockIdx.y, m = blockIdx.z;
    const float* src = m ? src1 : src0;
    __bf16* dst = m ? dst1 : dst0;
    int tid = threadIdx.x;
    __shared__ float tile[32][133];
    int kr = tid >> 3, nc0 = (tid & 7) * 16;
    const f32x4* s4 = (const f32x4*)(src + (size_t)(kc * 32 + kr) * 12288 + nb * 128 + nc0);
    f32x4 v0 = s4[0], v1 = s4[1], v2 = s4[2], v3 = s4[3];
#pragma unroll
    for (int r = 0; r < 4; ++r) {
        tile[kr][nc0 + r]      = v0[r];
        tile[kr][nc0 + 4 + r]  = v1[r];
        tile[kr][nc0 + 8 + r]  = v2[r];
        tile[kr][nc0 + 12 + r] = v3[r];
    }
    __syncthreads();
    __bf16* db = dst + (size_t)(nb * 96 + kc) * 4096;
#pragma unroll
    for (int c = 0; c < 2; ++c) {
        int lidx = tid * 2 + c;
        int sub = lidx >> 6, lane = lidx & 63;
        int kb = (lane >> 4) * 8, nn = sub * 16 + (lane & 15);
        v8bf o;
#pragma unroll
        for (int j = 0; j < 8; ++j) o[j] = (__bf16)tile[kb + j][nn];
        ((v8bf*)db)[lidx] = o;
    }
}

// [3072,12288] fp32 -> R-pack, UNIT-CONTIGUOUS: v8bf index ((nt*96+kc)*4+i)*64+lane,
// where column-tile ct = nb*8+sub = i*192+nt. Each step unit (stack,nt) then reads a
// contiguous 384KB slice; each wave a contiguous 48KB run.
__global__ __launch_bounds__(256) void pack_R_kernel(const float* __restrict__ src0,
                                                     const float* __restrict__ src1,
                                                     __bf16* __restrict__ dst0,
                                                     __bf16* __restrict__ dst1) {
    int nb = blockIdx.x, kc = blockIdx.y, m = blockIdx.z;
    const float* src = m ? src1 : src0;
    __bf16* dst = m ? dst1 : dst0;
    int tid = threadIdx.x;
    __shared__ float tile[32][133];
    int kr = tid >> 3, nc0 = (tid & 7) * 16;
    const f32x4* s4 = (const f32x4*)(src + (size_t)(kc * 32 + kr) * 12288 + nb * 128 + nc0);
    f32x4 v0 = s4[0], v1 = s4[1], v2 = s4[2], v3 = s4[3];
#pragma unroll
    for (int r = 0; r < 4; ++r) {
        tile[kr][nc0 + r]      = v0[r];
        tile[kr][nc0 + 4 + r]  = v1[r];
        tile[kr][nc0 + 8 + r]  = v2[r];
        tile[kr][nc0 + 12 + r] = v3[r];
    }
    __syncthreads();
#pragma unroll
    for (int c = 0; c < 2; ++c) {
        int lidx = tid * 2 + c;
        int sub = lidx >> 6, lane = lidx & 63;
        int kb = (lane >> 4) * 8, nn = sub * 16 + (lane & 15);
        v8bf o;
#pragma unroll
        for (int j = 0; j < 8; ++j) o[j] = (__bf16)tile[kb + j][nn];
        int ct = nb * 8 + sub;
        int nt = ct % 192, fi = ct / 192;
        size_t off = (((size_t)nt * 96 + kc) * 4 + fi) * 64 + lane;
        ((v8bf*)dst)[off] = o;
    }
}

// pre = seq @ W, 128x128 tile, BK=32, BOTH operands pre-packed bf16 via global_load_lds.
__global__ __launch_bounds__(256) void pre_gemm_packed(const __bf16* __restrict__ Apack,
                                                       const __bf16* __restrict__ Bp0,
                                                       const __bf16* __restrict__ Bp1,
                                                       __bf16* __restrict__ preP) {
    int nb = blockIdx.x, mb = blockIdx.y, stack = blockIdx.z;
    const char* Bpack = (const char*)(stack ? Bp1 : Bp0);
    int tid = threadIdx.x, wave = tid >> 6, lane = tid & 63;
    __shared__ alignas(16) __bf16 As[4096];
    __shared__ alignas(16) __bf16 Bs[4096];
    f32x4 acc[4][4];
#pragma unroll
    for (int i = 0; i < 4; ++i)
#pragma unroll
        for (int j = 0; j < 4; ++j) acc[i][j] = 0.0f;

    for (int kc = 0; kc < 96; ++kc) {
        size_t atile = (size_t)(mb * 96 + kc) * 8192;
        size_t btile = (size_t)(nb * 96 + kc) * 8192;
        int chunk = wave * 2048;
        gl_lds16((const char*)Apack + atile + chunk + lane * 16,        (char*)As + chunk);
        gl_lds16((const char*)Apack + atile + chunk + 1024 + lane * 16, (char*)As + chunk + 1024);
        gl_lds16(Bpack + btile + chunk + lane * 16,        (char*)Bs + chunk);
        gl_lds16(Bpack + btile + chunk + 1024 + lane * 16, (char*)Bs + chunk + 1024);
        __syncthreads();
        const v8bf* A8 = (const v8bf*)As;
        const v8bf* B8 = (const v8bf*)Bs;
        v8bf a[4], b[4];
#pragma unroll
        for (int mi = 0; mi < 4; ++mi) a[mi] = A8[((wave >> 1) * 4 + mi) * 64 + lane];
#pragma unroll
        for (int ni = 0; ni < 4; ++ni) b[ni] = B8[((wave & 1) * 4 + ni) * 64 + lane];
#pragma unroll
        for (int mi = 0; mi < 4; ++mi)
#pragma unroll
            for (int ni = 0; ni < 4; ++ni) acc[mi][ni] = MFMA16(a[mi], b[ni], acc[mi][ni]);
        __syncthreads();
    }
#pragma unroll
    for (int mi = 0; mi < 4; ++mi)
#pragma unroll
        for (int ni = 0; ni < 4; ++ni) {
            int mt = mb * 8 + (wave >> 1) * 4 + mi;   // == t
            int nt4 = nb * 8 + (wave & 1) * 4 + ni;   // n-tile in [0,768)
            v4bf o;
#pragma unroll
            for (int r = 0; r < 4; ++r) o[r] = (__bf16)acc[mi][ni][r];
            ((v4bf*)preP)[(((size_t)stack * 48 + mt) * 768 + nt4) * 64 + lane] = o;
        }
}

// Fallback (small ws): pre = seq @ W with W read as fp32 (transpose+cvt in LDS).
__global__ __launch_bounds__(256) void pre_gemm(const __bf16* __restrict__ Apack,
                                                const float* __restrict__ W1,
                                                const float* __restrict__ W2,
                                                __bf16* __restrict__ preP) {
    int nb = blockIdx.x, mb = blockIdx.y, stack = blockIdx.z;
    const float* W = stack ? W2 : W1;
    int tid = threadIdx.x, wave = tid >> 6, lane = tid & 63;
    __shared__ alignas(16) __bf16 As[4096];
    __shared__ alignas(16) __bf16 Bs[4096];
    __shared__ float tile[32][133];
    f32x4 acc[4][4];
#pragma unroll
    for (int i = 0; i < 4; ++i)
#pragma unroll
        for (int j = 0; j < 4; ++j) acc[i][j] = 0.0f;

    int kr = tid >> 3, nc0 = (tid & 7) * 16;
    for (int kc = 0; kc < 96; ++kc) {
        size_t atile = (size_t)(mb * 96 + kc) * 8192;
        int chunk = wave * 2048;
        gl_lds16((const char*)Apack + atile + chunk + lane * 16,        (char*)As + chunk);
        gl_lds16((const char*)Apack + atile + chunk + 1024 + lane * 16, (char*)As + chunk + 1024);
        const f32x4* s4 = (const f32x4*)(W + (size_t)(kc * 32 + kr) * 12288 + nb * 128 + nc0);
        f32x4 v0 = s4[0], v1 = s4[1], v2 = s4[2], v3 = s4[3];
#pragma unroll
        for (int r = 0; r < 4; ++r) {
            tile[kr][nc0 + r]      = v0[r];
            tile[kr][nc0 + 4 + r]  = v1[r];
            tile[kr][nc0 + 8 + r]  = v2[r];
            tile[kr][nc0 + 12 + r] = v3[r];
        }
        __syncthreads();
#pragma unroll
        for (int c = 0; c < 2; ++c) {
            int lidx = tid * 2 + c;
            int sub = lidx >> 6, l2 = lidx & 63;
            int kb = (l2 >> 4) * 8, nn = sub * 16 + (l2 & 15);
            v8bf o;
#pragma unroll
            for (int j = 0; j < 8; ++j) o[j] = (__bf16)tile[kb + j][nn];
            ((v8bf*)Bs)[lidx] = o;
        }
        __syncthreads();
        const v8bf* A8 = (const v8bf*)As;
        const v8bf* B8 = (const v8bf*)Bs;
        v8bf a[4], b[4];
#pragma unroll
        for (int mi = 0; mi < 4; ++mi) a[mi] = A8[((wave >> 1) * 4 + mi) * 64 + lane];
#pragma unroll
        for (int ni = 0; ni < 4; ++ni) b[ni] = B8[((wave & 1) * 4 + ni) * 64 + lane];
#pragma unroll
        for (int mi = 0; mi < 4; ++mi)
#pragma unroll
            for (int ni = 0; ni < 4; ++ni) acc[mi][ni] = MFMA16(a[mi], b[ni], acc[mi][ni]);
        __syncthreads();
    }
#pragma unroll
    for (int mi = 0; mi < 4; ++mi)
#pragma unroll
        for (int ni = 0; ni < 4; ++ni) {
            int mt = mb * 8 + (wave >> 1) * 4 + mi;
            int nt4 = nb * 8 + (wave & 1) * 4 + ni;
            v4bf o;
#pragma unroll
            for (int r = 0; r < 4; ++r) o[r] = (__bf16)acc[mi][ni][r];
            ((v4bf*)preP)[(((size_t)stack * 48 + mt) * 768 + nt4) * 64 + lane] = o;
        }
}

// One recurrence step: per (stack, nt): K-split over 8 waves reading the unit's
// CONTIGUOUS R slice (wave = contiguous 48KB), LDS combine, wave 0 does gates.
__global__ __launch_bounds__(512) void step_kernel(
    const __bf16* __restrict__ Rp0, const __bf16* __restrict__ Rp1,
    const __bf16* __restrict__ hread, __bf16* __restrict__ hwrite,
    const __bf16* __restrict__ preP,
    const float* __restrict__ bias1, const float* __restrict__ bias2,
    float* __restrict__ cbuf, float* __restrict__ nbuf, float* __restrict__ mbuf,
    float* __restrict__ ysum, int t) {
    int nt = blockIdx.x, stack = blockIdx.y;
    int tid = threadIdx.x, wave = tid >> 6, lane = tid & 63;
    const v8bf* Rp = (const v8bf*)(stack ? Rp1 : Rp0);
    const v8bf* hA = (const v8bf*)hread + (size_t)stack * 96 * 64;
    size_t base0 = (size_t)nt * 24576 + lane;      // unit slice start (v8bf units)
    int kcs = wave * 12;
    f32x4 acc[4];
#pragma unroll
    for (int i = 0; i < 4; ++i) acc[i] = 0.0f;

    // depth-1 prefetch over the wave's contiguous 48KB run
    v8bf a0 = hA[(size_t)kcs * 64 + lane];
    v8bf bf[4];
#pragma unroll
    for (int i = 0; i < 4; ++i) bf[i] = Rp[base0 + (size_t)kcs * 256 + i * 64];
    for (int kk = 0; kk < 12; ++kk) {
        v8bf a1 = a0;
        v8bf bn[4];
        if (kk < 11) {
            int kc1 = kcs + kk + 1;
            a1 = hA[(size_t)kc1 * 64 + lane];
#pragma unroll
            for (int i = 0; i < 4; ++i) bn[i] = Rp[base0 + (size_t)kc1 * 256 + i * 64];
        } else {
#pragma unroll
            for (int i = 0; i < 4; ++i) bn[i] = bf[i];
        }
#pragma unroll
        for (int i = 0; i < 4; ++i) acc[i] = MFMA16(a0, bf[i], acc[i]);
        a0 = a1;
#pragma unroll
        for (int i = 0; i < 4; ++i) bf[i] = bn[i];
    }

    __shared__ f32x4 red4[8][4][64];
#pragma unroll
    for (int i = 0; i < 4; ++i) red4[wave][i][lane] = acc[i];
    __syncthreads();

    if (wave == 0) {
        const float* bias = stack ? bias2 : bias1;
        f32x4 g[4];
#pragma unroll
        for (int i = 0; i < 4; ++i) {
            f32x4 s = red4[0][i][lane];
#pragma unroll
            for (int w = 1; w < 8; ++w) s += red4[w][i][lane];
            g[i] = s;
        }
        int fcol = nt * 16 + (lane & 15);
        int bq = (lane >> 4) * 4;
#pragma unroll
        for (int i = 0; i < 4; ++i) {
            v4bf pv = ((const v4bf*)preP)[(((size_t)stack * 48 + t) * 768 + (i * 192 + nt)) * 64 + lane];
            float bv = bias[i * 3072 + fcol];
#pragma unroll
            for (int r = 0; r < 4; ++r) g[i][r] += (float)pv[r] + bv;
        }
        size_t sidx = ((size_t)stack * 192 + nt) * 64 + lane;
        f32x4 cc = ((f32x4*)cbuf)[sidx];
        f32x4 nn = ((f32x4*)nbuf)[sidx];
        f32x4 mm = ((f32x4*)mbuf)[sidx];
        int kc = fcol >> 5, ko = fcol & 31;
        __bf16* hw = hwrite + ((size_t)stack * 96 + kc) * 512 + (size_t)(ko >> 3) * 128 + (ko & 7);
        int flat = t * 3072 + fcol;
        int cch = flat / 2304;
        int rem = flat - cch * 2304;
        int u = rem / 48;
        int v = rem - u * 48;
        int yidx = cch * 48 + (stack ? u : v);  // stack1=y2 -> x_h over u ; stack0=y1 -> x_w over v
        float* yb = ysum + (size_t)stack * 16 * 3072;
#pragma unroll
        for (int r = 0; r < 4; ++r) {
            int brow = bq + r;
            float it = g[0][r], ft = g[1][r], zt = g[2][r], ot = g[3][r];
            float mnew = fmaxf(ft + mm[r], it);
            float iv = __expf(it - mnew);
            float fv = __expf(ft + mm[r] - mnew);
            float cnew = fv * cc[r] + iv * tanhf(zt);
            float nnew = fv * nn[r] + iv;
            float sg = 1.0f / (1.0f + __expf(-ot));
            float h = sg * cnew / (nnew + 1e-6f);
            cc[r] = cnew; nn[r] = nnew; mm[r] = mnew;
            hw[(size_t)brow * 8] = (__bf16)h;
            atomicAdd(yb + (size_t)brow * 3072 + yidx, h);
        }
        ((f32x4*)cbuf)[sidx] = cc;
        ((f32x4*)nbuf)[sidx] = nn;
        ((f32x4*)mbuf)[sidx] = mm;
    }
}

// grouped conv1d (K=5, 8 groups of 8ch) + GroupNorm(16 groups) + sigmoid, per (which, b)
__global__ __launch_bounds__(256) void conv_gn_kernel(const float* __restrict__ ysum,
                                                      const float* __restrict__ cw,
                                                      const float* __restrict__ gamma,
                                                      const float* __restrict__ beta,
                                                      float* __restrict__ gatebuf) {
    int bi = blockIdx.x;
    int s = bi >> 4, b = bi & 15;
    int tid = threadIdx.x;
    __shared__ float in0[3072], cvout[3072], cws[2560];
    __shared__ float r1[16][16], r2[16][16], mu_s[16], rs_s[16];
    const float* src = ysum + (size_t)(s * 16 + b) * 3072;
    for (int e = tid; e < 3072; e += 256) in0[e] = src[e] * (1.0f / 48.0f);
    for (int e = tid; e < 2560; e += 256) cws[e] = cw[e];
    __syncthreads();
    for (int e = tid; e < 3072; e += 256) {
        int co = e / 48, p = e - co * 48;
        int g = co >> 3;
        const float* wrow = cws + co * 40;
        const float* irow = in0 + g * 8 * 48;
        float a = 0.f;
#pragma unroll
        for (int ci = 0; ci < 8; ++ci)
#pragma unroll
            for (int q = 0; q < 5; ++q) {
                int pp = p + q - 2;
                if (pp >= 0 && pp < 48) a += wrow[ci * 5 + q] * irow[ci * 48 + pp];
            }
        cvout[e] = a;
    }
    __syncthreads();
    int gn = tid >> 4, ln = tid & 15;
    float s1 = 0.f, s2 = 0.f;
    for (int ii = ln; ii < 192; ii += 16) {
        float v = cvout[gn * 192 + ii];
        s1 += v; s2 += v * v;
    }
    r1[gn][ln] = s1; r2[gn][ln] = s2;
    __syncthreads();
    if (tid < 16) {
        float a = 0.f, c2 = 0.f;
        for (int ii = 0; ii < 16; ++ii) { a += r1[tid][ii]; c2 += r2[tid][ii]; }
        float mu = a * (1.0f / 192.0f);
        float var = c2 * (1.0f / 192.0f) - mu * mu;
        mu_s[tid] = mu;
        rs_s[tid] = rsqrtf(var + 1e-5f);
    }
    __syncthreads();
    float* dst = gatebuf + (size_t)(s * 16 + b) * 3072;
    for (int e = tid; e < 3072; e += 256) {
        int c = e / 48;
        int gg = c >> 2;
        float xn = (cvout[e] - mu_s[gg]) * rs_s[gg] * gamma[c] + beta[c];
        dst[e] = 1.0f / (1.0f + __expf(-xn));
    }
}

__global__ __launch_bounds__(256) void final_kernel(const float* __restrict__ x,
                                                    const float* __restrict__ gatebuf,
                                                    float* __restrict__ out) {
    int gid = blockIdx.x * 256 + threadIdx.x;  // < 589824 float4s
    int wi4 = gid % 12;
    int rest = gid / 12;
    int hi = rest % 48;
    int bc = rest / 48;
    int b = bc >> 6, c = bc & 63;
    f32x4 xv = ((const f32x4*)x)[gid];
    float gh = gatebuf[(size_t)(16 + b) * 3072 + c * 48 + hi];        // s=1 (y2) -> x_h[hi]
    f32x4 gw = *(const f32x4*)(gatebuf + (size_t)b * 3072 + c * 48 + wi4 * 4);  // s=0 -> x_w[wi]
    f32x4 o;
#pragma unroll
    for (int k = 0; k < 4; ++k) o[k] = xv[k] * gh * gw[k];
    ((f32x4*)out)[gid] = o;
}

extern "C" void kernel_launch(void* const* d_in, const int* in_sizes, int n_in,
                              void* d_out, int out_size, void* d_ws, size_t ws_size,
                              hipStream_t stream) {
    const float* x     = (const float*)d_in[0];
    const float* W1    = (const float*)d_in[1];
    const float* R1    = (const float*)d_in[2];
    const float* b1    = (const float*)d_in[3];
    const float* W2    = (const float*)d_in[4];
    const float* R2    = (const float*)d_in[5];
    const float* b2    = (const float*)d_in[6];
    const float* cw    = (const float*)d_in[7];
    const float* gamma = (const float*)d_in[8];
    const float* beta  = (const float*)d_in[9];

    char* ws = (char*)d_ws;
    __bf16* seqA = (__bf16*)d_out;               // scratch; dead after pre_gemm
    __bf16* preP = (__bf16*)(ws + OFF_PREP);
    __bf16* h0   = (__bf16*)(ws + OFF_H0);
    __bf16* h1   = (__bf16*)(ws + OFF_H1);
    float* cbuf  = (float*)(ws + OFF_C);
    float* nbuf  = (float*)(ws + OFF_N);
    float* mbuf  = (float*)(ws + OFF_M);
    float* ysum  = (float*)(ws + OFF_YS);
    float* gate  = (float*)(ws + OFF_GATE);

    bool big_ws = ws_size >= END_A;   // verified on harness (rounds 0/2/3/4/6)
    __bf16* PA = (__bf16*)(ws + OFF_RA);   // pack region (time-shared: W-pack then R-pack)
    __bf16* PB = (__bf16*)(ws + OFF_RB);

    pack_x_kernel<<<1152, 256, 0, stream>>>(x, seqA);
    if (big_ws) {
        // Phase 1: W packs occupy the pack region, consumed immediately by the bf16 GEMM.
        pack_B_kernel<<<dim3(96, 96, 2), 256, 0, stream>>>(W1, W2, PA, PB);
        pre_gemm_packed<<<dim3(96, 6, 2), 256, 0, stream>>>(seqA, PA, PB, preP);
        // Phase 2: R packs (unit-contiguous layout) overwrite the same region.
        pack_R_kernel<<<dim3(96, 96, 2), 256, 0, stream>>>(R1, R2, PA, PB);
    } else {
        pre_gemm<<<dim3(96, 6, 2), 256, 0, stream>>>(seqA, W1, W2, preP);
        pack_R_kernel<<<dim3(96, 96, 2), 256, 0, stream>>>(R1, R2, PA, PB);
    }
    zero_kernel<<<480, 256, 0, stream>>>((f32x4*)(ws + OFF_H0), 122880);
    for (int t = 0; t < 48; ++t) {
        const __bf16* hr = (t & 1) ? h1 : h0;
        __bf16* hw       = (t & 1) ? h0 : h1;
        step_kernel<<<dim3(192, 2), 512, 0, stream>>>(PA, PB, hr, hw, preP, b1, b2,
                                                      cbuf, nbuf, mbuf, ysum, t);
    }
    conv_gn_kernel<<<32, 256, 0, stream>>>(ysum, cw, gamma, beta, gate);
    final_kernel<<<2304, 256, 0, stream>>>(x, gate, (float*)d_out);
}